// Round 8
// baseline (943.780 us; speedup 1.0000x reference)
//
#include <hip/hip_runtime.h>

// Model: conv(32x2,s2) -> conv(32x9,s2) -> GRU encoder (105 steps) ->
//        attention decoder (63 steps) -> fc.  B=64,H=128,V=32.

typedef float f32x4 __attribute__((ext_vector_type(4)));
typedef short s16x8 __attribute__((ext_vector_type(8)));
typedef unsigned int u32x4 __attribute__((ext_vector_type(4)));

static __device__ __forceinline__ unsigned short f2b(float f) {
  unsigned int u = __float_as_uint(f);
  unsigned int r = u + 0x7fffu + ((u >> 16) & 1u);
  return (unsigned short)(r >> 16);
}
static __device__ __forceinline__ float sigmoidf_(float x) {
  return 1.0f / (1.0f + __expf(-x));
}
static __device__ __forceinline__ float tanhf_(float x) {
  float ax = fabsf(x);
  float t = __expf(-2.0f * ax);
  float r = (1.0f - t) / (1.0f + t);
  return x >= 0.0f ? r : -r;
}
static __device__ __forceinline__ float blo(unsigned int w) {
  return __uint_as_float(w << 16);
}
static __device__ __forceinline__ float bhi(unsigned int w) {
  return __uint_as_float(w & 0xffff0000u);
}

// ---------------- weight pre-transforms (re-run every launch; ws is re-poisoned) ----
__global__ __launch_bounds__(256) void prep_kernel(
    const float* __restrict__ w2, const float* __restrict__ wih,
    const float* __restrict__ whh, const float* __restrict__ dwhh,
    const float* __restrict__ dwih,
    unsigned short* __restrict__ wt2, unsigned short* __restrict__ wihB,
    unsigned int* __restrict__ wpe, unsigned int* __restrict__ wpd,
    float* __restrict__ wdT) {
  int idx = blockIdx.x * 256 + threadIdx.x;
  if (idx < 294912) {
    int ci = idx & 31;
    int n = (idx >> 5) & 31;
    int kk = idx >> 10;          // kt*9+kf
    int kf = kk % 9, kt = kk / 9;
    wt2[idx] = f2b(w2[((n * 32 + ci) * 32 + kt) * 9 + kf]);
  } else if (idx < 737280) {
    int i = idx - 294912;
    wihB[i] = f2b(wih[i]);
  } else if (idx < 761856) {
    int i = idx - 737280;
    int j = i % 384, k2 = i / 384;
    unsigned int lo = f2b(whh[j * 128 + 2 * k2]);
    unsigned int hi = f2b(whh[j * 128 + 2 * k2 + 1]);
    wpe[i] = lo | (hi << 16);
  } else if (idx < 786432) {
    int i = idx - 761856;
    int j = i % 384, k2 = i / 384;
    unsigned int lo = f2b(dwhh[j * 128 + 2 * k2]);
    unsigned int hi = f2b(dwhh[j * 128 + 2 * k2 + 1]);
    wpd[i] = lo | (hi << 16);
  } else if (idx < 798720) {
    int i = idx - 786432;
    int j = i % 384, e = i / 384;
    wdT[i] = dwih[j * 32 + e];
  }
}

// ---------------- conv1 v2: row-reuse register-blocked, out [b][t][f][c] bf16 -------
__global__ __launch_bounds__(256) void conv1_kernel(
    const float* __restrict__ x, const float* __restrict__ mean,
    const float* __restrict__ stdv, const float* __restrict__ w1,
    const float* __restrict__ b1, unsigned short* __restrict__ c1out) {
  __shared__ float ins[46][162];
  __shared__ float meanL[161];
  __shared__ float rstdL[161];
  int tid = threadIdx.x;
  int tt = blockIdx.x;        // 0..30
  int b = blockIdx.y;         // 0..63
  int t0 = tt * 8;
  if (tid < 161) {
    meanL[tid] = mean[tid];
    rstdL[tid] = 1.0f / stdv[tid];
  }
  int fs = tid >> 4, cg = tid & 15;
  int c0 = 2 * cg;
  float wA[64], wB[64];
  {
    const float4* wa = (const float4*)(w1 + c0 * 64);
    const float4* wb = (const float4*)(w1 + (c0 + 1) * 64);
#pragma unroll
    for (int i = 0; i < 16; ++i) {
      float4 va = wa[i], vb = wb[i];
      wA[4 * i] = va.x; wA[4 * i + 1] = va.y; wA[4 * i + 2] = va.z; wA[4 * i + 3] = va.w;
      wB[4 * i] = vb.x; wB[4 * i + 1] = vb.y; wB[4 * i + 2] = vb.z; wB[4 * i + 3] = vb.w;
    }
  }
  float biasA = b1[c0], biasB = b1[c0 + 1];
  __syncthreads();   // meanL/rstdL ready

  const float* xb = x + ((size_t)b * 512 + 2 * t0) * 161;
  int nrows = 512 - 2 * t0; if (nrows > 46) nrows = 46;
  for (int i = tid; i < 46 * 161; i += 256) {
    int r = i / 161, col = i - r * 161;
    float v = (r < nrows) ? xb[(size_t)r * 161 + col] : 0.0f;
    ins[r][col] = (v - meanL[col]) * rstdL[col];
  }
  __syncthreads();

  int T = 241 - t0; if (T > 8) T = 8;
#pragma unroll
  for (int fi = 0; fi < 5; ++fi) {
    int f = fs + 16 * fi;
    float accA[8], accB[8];
#pragma unroll
    for (int t = 0; t < 8; ++t) { accA[t] = biasA; accB[t] = biasB; }
#pragma unroll
    for (int r = 0; r < 46; ++r) {
      float2 v = *(const float2*)&ins[r][2 * f];
#pragma unroll
      for (int t = 0; t < 8; ++t) {
        const int kt = r - 2 * t;
        if (kt >= 0 && kt < 32) {
          accA[t] = fmaf(v.x, wA[2 * kt], accA[t]);
          accA[t] = fmaf(v.y, wA[2 * kt + 1], accA[t]);
          accB[t] = fmaf(v.x, wB[2 * kt], accB[t]);
          accB[t] = fmaf(v.y, wB[2 * kt + 1], accB[t]);
        }
      }
    }
#pragma unroll
    for (int t = 0; t < 8; ++t) {
      if (t < T) {
        float a = accA[t] > 0.0f ? accA[t] : 0.0f;
        float bb = accB[t] > 0.0f ? accB[t] : 0.0f;
        unsigned int pk = (unsigned int)f2b(a) | ((unsigned int)f2b(bb) << 16);
        *(unsigned int*)&c1out[(((size_t)b * 241 + t0 + t) * 80 + f) * 32 + c0] = pk;
      }
    }
  }
}

// ---------------- conv2 v3: LDS ring-buffer implicit GEMM --------------------------
__global__ __launch_bounds__(256) void conv2_kernel(
    const unsigned short* __restrict__ c1out, const unsigned short* __restrict__ wt2,
    const float* __restrict__ b2, unsigned short* __restrict__ X2) {
  __shared__ int ldsA[8 * 360 * 4];   // 8 slots x 360 16B-chunks = 46,080 B
  int tid = threadIdx.x;
  int lane = tid & 63, wave = tid >> 6;
  int quad = lane >> 4, l16 = lane & 15;
  int j = blockIdx.x;       // 0..14
  int b = blockIdx.y;       // 0..63

  int tlA[4], baseA[4];
#pragma unroll
  for (int mt = 0; mt < 4; ++mt) {
    int ml = wave * 64 + mt * 16 + l16;
    if (ml > 251) ml = 251;
    int tl = ml / 36;
    int f2 = ml - tl * 36;
    tlA[mt] = tl;
    baseA[mt] = (9 * f2 + quad) * 4;
  }
  const unsigned short* bp = wt2 + l16 * 32 + quad * 8;

  f32x4 zero = {0.f, 0.f, 0.f, 0.f};
  f32x4 acc[4][2];
#pragma unroll
  for (int mt = 0; mt < 4; ++mt) {
    acc[mt][0] = zero;
    acc[mt][1] = zero;
  }

  const size_t rowsh = 2560;  // shorts per t-row (80*32)
  const unsigned short* gbase = c1out + ((size_t)b * 241 + 14 * j) * rowsh;

  for (int p = 0; p < 2; ++p) {
#pragma unroll
    for (int k = 0; k < 9; ++k) {
      int i = tid + 256 * k;
      if (i < 2240) {
        int h = i / 320, r = i - 320 * h;
        int4 v = *(const int4*)(gbase + (size_t)(p + 2 * h) * rowsh + r * 8);
        *((int4*)&ldsA[(h * 360 + r + (r >> 3)) * 4]) = v;
      }
    }
    for (int k = 0; k < 16; ++k) {
      int kt = 2 * k + p;
      if (k > 0) {
        int slot = (k + 6) & 7;
        const unsigned short* g = gbase + (size_t)(p + 2 * (k + 6)) * rowsh;
        int r = tid;
        int4 v = *(const int4*)(g + r * 8);
        *((int4*)&ldsA[(slot * 360 + r + (r >> 3)) * 4]) = v;
        if (tid < 64) {
          int r2 = 256 + tid;
          int4 v2 = *(const int4*)(g + r2 * 8);
          *((int4*)&ldsA[(slot * 360 + r2 + (r2 >> 3)) * 4]) = v2;
        }
      }
      __syncthreads();
      const unsigned short* bk = bp + (size_t)kt * 9216;
#pragma unroll
      for (int kf = 0; kf < 9; ++kf) {
        s16x8 b0 = *(const s16x8*)(bk + kf * 1024);
        s16x8 b1v = *(const s16x8*)(bk + kf * 1024 + 512);
        int kfo = (4 * kf + (kf >> 1)) * 4;
#pragma unroll
        for (int mt = 0; mt < 4; ++mt) {
          int slot = (k + tlA[mt]) & 7;
          s16x8 a = *(const s16x8*)&ldsA[slot * 1440 + baseA[mt] + kfo];
          acc[mt][0] = __builtin_amdgcn_mfma_f32_16x16x32_bf16(a, b0, acc[mt][0], 0, 0, 0);
          acc[mt][1] = __builtin_amdgcn_mfma_f32_16x16x32_bf16(a, b1v, acc[mt][1], 0, 0, 0);
        }
      }
    }
    __syncthreads();
  }

#pragma unroll
  for (int nt = 0; nt < 2; ++nt) {
    int n = nt * 16 + l16;
    float bias = b2[n];
#pragma unroll
    for (int mt = 0; mt < 4; ++mt) {
      f32x4 v = acc[mt][nt];
#pragma unroll
      for (int r = 0; r < 4; ++r) {
        int ml = wave * 64 + mt * 16 + quad * 4 + r;
        if (ml < 252) {
          int tl = ml / 36;
          int f2 = ml - tl * 36;
          int t2 = 7 * j + tl;
          float val = v[r] + bias;
          val = val > 0.0f ? val : 0.0f;
          X2[((size_t)(b * 105 + t2) * 32 + n) * 36 + f2] = f2b(val);
        }
      }
    }
  }
}

// ---------------- xp GEMM: xp[(b,t2)][j] = X2 @ w_ih^T + b_ih, M=6720,N=384,K=1152 ---
__global__ __launch_bounds__(256) void xp_kernel(
    const unsigned short* __restrict__ X2, const unsigned short* __restrict__ wihB,
    const float* __restrict__ bih, float* __restrict__ xp) {
  int tid = threadIdx.x;
  int lane = tid & 63, wave = tid >> 6;
  int quad = lane >> 4, l16 = lane & 15;
  int m_tile = blockIdx.x * 4 + wave;   // 0..419
  int n0 = blockIdx.y * 128;
  int row = m_tile * 16 + l16;
  const unsigned short* apb = X2 + (size_t)row * 1152 + quad * 8;
  const unsigned short* bpb = wihB + (size_t)(n0 + l16) * 1152 + quad * 8;
  f32x4 zero = {0.f, 0.f, 0.f, 0.f};
  f32x4 acc[8];
#pragma unroll
  for (int nt = 0; nt < 8; ++nt) acc[nt] = zero;
  for (int ks = 0; ks < 36; ++ks) {
    s16x8 a = *(const s16x8*)(apb + ks * 32);
#pragma unroll
    for (int nt = 0; nt < 8; ++nt) {
      s16x8 bb = *(const s16x8*)(bpb + (size_t)nt * 16 * 1152 + ks * 32);
      acc[nt] = __builtin_amdgcn_mfma_f32_16x16x32_bf16(a, bb, acc[nt], 0, 0, 0);
    }
  }
#pragma unroll
  for (int nt = 0; nt < 8; ++nt) {
    int n = n0 + nt * 16 + l16;
    float bias = bih[n];
#pragma unroll
    for (int r = 0; r < 4; ++r) {
      int m = m_tile * 16 + quad * 4 + r;
      xp[(size_t)m * 384 + n] = acc[nt][r] + bias;
    }
  }
}

// ---------------- ip: emb[y] @ dec_w_ih^T + b ---------------------------------------
__global__ __launch_bounds__(384) void ip_kernel(
    const int* __restrict__ y, const float* __restrict__ emb,
    const float* __restrict__ wdT, const float* __restrict__ dbih,
    float* __restrict__ ipg) {
  __shared__ float er[32];
  int bs = blockIdx.x;
  int b = bs / 63, s = bs - b * 63;
  int tid = threadIdx.x;
  if (tid < 32) er[tid] = emb[(size_t)y[b * 64 + s] * 32 + tid];
  __syncthreads();
  float acc = dbih[tid];
#pragma unroll
  for (int e = 0; e < 32; ++e) acc = fmaf(er[e], wdT[e * 384 + tid], acc);
  ipg[(size_t)bs * 384 + tid] = acc;
}

// ---------------- fused RNN v2: bf16 dual-layout attention --------------------------
// eh stored twice in bf16: ehR[t][d] (scores, b128 rows) and ehTb[d][t] (ctx, b128
// rows over t). Pitch 136 shorts = 17 chunks -> chunk-starts cycle all 8 bank groups.
// hx2 and softmax numerators also bf16 (hx2h, a_b); unpack via blo/bhi fma.
__global__ __launch_bounds__(384) void rnn_kernel(
    const float* __restrict__ xp, const unsigned int* __restrict__ wpe,
    const float* __restrict__ bhh, const float* __restrict__ ipg,
    const unsigned int* __restrict__ wpd, const float* __restrict__ dbhh,
    const float* __restrict__ fcw, const float* __restrict__ fcb,
    float* __restrict__ outg) {
  __shared__ __align__(16) unsigned short ehR[105 * 136];    // 28,560 B
  __shared__ __align__(16) unsigned short ehTb[128 * 136];   // 34,816 B
  __shared__ __align__(16) float gh_s[384];
  __shared__ __align__(16) float h_s[128];
  __shared__ __align__(16) unsigned short hx2h[128];
  __shared__ float s_s[112];
  __shared__ __align__(16) unsigned short a_b[128];
  __shared__ float red_s[1];
  int tid = threadIdx.x, b = blockIdx.x;

  // ================= encoder =================
  unsigned int w[64];
#pragma unroll
  for (int k2 = 0; k2 < 64; ++k2) w[k2] = wpe[k2 * 384 + tid];
  float bias = bhh[tid];
  if (tid < 128) h_s[tid] = 0.0f;
  if (tid < 128) a_b[tid] = 0;               // t>=105 pads stay 0 forever
  for (int i = tid; i < 128 * 31; i += 384) { // zero ehTb pad t=105..135
    int d = i / 31, t = 105 + (i - (i / 31) * 31);
    ehTb[d * 136 + t] = 0;
  }
  __syncthreads();

  const float* xpb = xp + (size_t)b * 105 * 384;
  float nxg = (tid < 256) ? xpb[tid] : 0.0f;
  float nxn = (tid < 128) ? xpb[tid + 256] : 0.0f;
  for (int t = 0; t < 105; ++t) {
    float cxg = nxg, cxn = nxn;
    if (t < 104) {
      const float* xpt = xpb + (size_t)(t + 1) * 384;
      nxg = (tid < 256) ? xpt[tid] : 0.0f;
      nxn = (tid < 128) ? xpt[tid + 256] : 0.0f;
    }
    float a0 = bias, a1 = 0.0f;
#pragma unroll
    for (int k4 = 0; k4 < 32; ++k4) {
      float4 h4 = *(const float4*)&h_s[4 * k4];
      unsigned int wa = w[2 * k4], wb = w[2 * k4 + 1];
      a0 = fmaf(h4.x, blo(wa), a0);
      a1 = fmaf(h4.y, bhi(wa), a1);
      a0 = fmaf(h4.z, blo(wb), a0);
      a1 = fmaf(h4.w, bhi(wb), a1);
    }
    float acc = a0 + a1;
    gh_s[tid] = (tid < 256) ? sigmoidf_(cxg + acc) : acc;
    __syncthreads();
    if (tid < 128) {
      float r = gh_s[tid], z = gh_s[tid + 128], hnp = gh_s[tid + 256];
      float nn = tanhf_(cxn + r * hnp);
      float hn = (1.0f - z) * nn + z * h_s[tid];
      h_s[tid] = hn;
      unsigned short hb = f2b(hn);
      ehR[t * 136 + tid] = hb;
      ehTb[tid * 136 + t] = hb;
    }
    __syncthreads();
  }

  // ================= decoder =================
#pragma unroll
  for (int k2 = 0; k2 < 64; ++k2) w[k2] = wpd[k2 * 384 + tid];
  bias = dbhh[tid];
  float wf[32];
  float fcbv = 0.0f;
  int fv = 0, fp = 0;
  if (tid >= 256) {
    int i = tid - 256;
    fp = i & 3; fv = i >> 2;
#pragma unroll
    for (int d = 0; d < 32; ++d) wf[d] = fcw[fv * 128 + fp * 32 + d];
    fcbv = fcb[fv];
  }
  if (tid < 128) h_s[tid] = 0.0f;
  __syncthreads();

  const float* ipb = ipg + (size_t)b * 63 * 384;
  nxg = (tid < 256) ? ipb[tid] : 0.0f;
  nxn = (tid < 128) ? ipb[tid + 256] : 0.0f;
  for (int s = 0; s < 63; ++s) {
    float cxg = nxg, cxn = nxn;
    if (s < 62) {
      const float* ipt = ipb + (size_t)(s + 1) * 384;
      nxg = (tid < 256) ? ipt[tid] : 0.0f;
      nxn = (tid < 128) ? ipt[tid + 256] : 0.0f;
    }
    // ---- GEMV ----
    float a0 = bias, a1 = 0.0f;
#pragma unroll
    for (int k4 = 0; k4 < 32; ++k4) {
      float4 h4 = *(const float4*)&h_s[4 * k4];
      unsigned int wa = w[2 * k4], wb = w[2 * k4 + 1];
      a0 = fmaf(h4.x, blo(wa), a0);
      a1 = fmaf(h4.y, bhi(wa), a1);
      a0 = fmaf(h4.z, blo(wb), a0);
      a1 = fmaf(h4.w, bhi(wb), a1);
    }
    float acc = a0 + a1;
    gh_s[tid] = (tid < 256) ? sigmoidf_(cxg + acc) : acc;
    __syncthreads();                     // (1) gh ready
    if (tid < 128) {
      float r = gh_s[tid], z = gh_s[tid + 128], hnp = gh_s[tid + 256];
      float nn = tanhf_(cxn + r * hnp);
      float hx2 = (1.0f - z) * nn + z * h_s[tid];
      hx2h[tid] = f2b(hx2);
    }
    __syncthreads();                     // (2) hx2h ready

    // ---- scores: bf16 b128 row reads of ehR ----
    if (tid < 210) {
      int row = tid >> 1, part = tid & 1;
      const u32x4* ep = (const u32x4*)&ehR[row * 136 + part * 64];
      const u32x4* hp = (const u32x4*)&hx2h[part * 64];
      float s0 = 0.f, s1 = 0.f, s2 = 0.f, s3 = 0.f;
#pragma unroll
      for (int c = 0; c < 8; ++c) {
        u32x4 e4 = ep[c], h4 = hp[c];
        s0 = fmaf(blo(e4[0]), blo(h4[0]), s0);
        s1 = fmaf(bhi(e4[0]), bhi(h4[0]), s1);
        s2 = fmaf(blo(e4[1]), blo(h4[1]), s2);
        s3 = fmaf(bhi(e4[1]), bhi(h4[1]), s3);
        s0 = fmaf(blo(e4[2]), blo(h4[2]), s0);
        s1 = fmaf(bhi(e4[2]), bhi(h4[2]), s1);
        s2 = fmaf(blo(e4[3]), blo(h4[3]), s2);
        s3 = fmaf(bhi(e4[3]), bhi(h4[3]), s3);
      }
      float sc = (s0 + s1) + (s2 + s3);
      sc += __shfl_xor(sc, 1);
      if (part == 0) s_s[row] = sc;
    }
    __syncthreads();                     // (3) s_s ready

    // ---- softmax (wave 0); a_b = bf16 numerators, rsum from f32 ----
    if (tid < 64) {
      float v0 = s_s[tid];
      float v1 = (tid < 41) ? s_s[tid + 64] : -1e30f;
      float m = fmaxf(v0, v1);
#pragma unroll
      for (int off = 32; off > 0; off >>= 1) m = fmaxf(m, __shfl_xor(m, off));
      float e0 = __expf(v0 - m);
      float e1 = (tid < 41) ? __expf(v1 - m) : 0.0f;
      a_b[tid] = f2b(e0);
      if (tid < 41) a_b[tid + 64] = f2b(e1);
      float sum = e0 + e1;
#pragma unroll
      for (int off = 32; off > 0; off >>= 1) sum += __shfl_xor(sum, off);
      if (tid == 0) red_s[0] = 1.0f / sum;
    }
    __syncthreads();                     // (4) a_b + rsum ready
    float rsum = red_s[0];

    // ---- ctx: bf16 b128 row reads of ehTb (t padded to 128, a_b pad = 0) ----
    if (tid < 256) {
      int d = tid >> 1, half = tid & 1;
      const u32x4* ep = (const u32x4*)&ehTb[d * 136 + half * 64];
      const u32x4* ap = (const u32x4*)&a_b[half * 64];
      float c0 = 0.f, c1 = 0.f, c2 = 0.f, c3 = 0.f;
#pragma unroll
      for (int cc = 0; cc < 8; ++cc) {
        u32x4 e4 = ep[cc], aa = ap[cc];
        c0 = fmaf(blo(e4[0]), blo(aa[0]), c0);
        c1 = fmaf(bhi(e4[0]), bhi(aa[0]), c1);
        c2 = fmaf(blo(e4[1]), blo(aa[1]), c2);
        c3 = fmaf(bhi(e4[1]), bhi(aa[1]), c3);
        c0 = fmaf(blo(e4[2]), blo(aa[2]), c0);
        c1 = fmaf(bhi(e4[2]), bhi(aa[2]), c1);
        c2 = fmaf(blo(e4[3]), blo(aa[3]), c2);
        c3 = fmaf(bhi(e4[3]), bhi(aa[3]), c3);
      }
      float c = (c0 + c1) + (c2 + c3);
      c += __shfl_xor(c, 1);
      if (half == 0) h_s[d] = c * rsum;  // carry = ctx
    }
    __syncthreads();                     // (5) hx (ctx) ready

    // ---- fc by threads 256..383 (off critical path) ----
    if (tid >= 256) {
      const float* cx = &h_s[fp * 32];
      float p0 = 0.f, p1 = 0.f;
#pragma unroll
      for (int d = 0; d < 32; d += 2) {
        p0 = fmaf(cx[d], wf[d], p0);
        p1 = fmaf(cx[d + 1], wf[d + 1], p1);
      }
      float p = p0 + p1;
      p += __shfl_xor(p, 1);
      p += __shfl_xor(p, 2);
      if (fp == 0) outg[((size_t)b * 63 + s) * 32 + fv] = fcbv + p;
    }
  }
}

extern "C" void kernel_launch(void* const* d_in, const int* in_sizes, int n_in,
                              void* d_out, int out_size, void* d_ws, size_t ws_size,
                              hipStream_t stream) {
  const float* x = (const float*)d_in[0];
  const int* y = (const int*)d_in[1];
  const float* mean = (const float*)d_in[2];
  const float* stdv = (const float*)d_in[3];
  const float* w1 = (const float*)d_in[4];
  const float* b1 = (const float*)d_in[5];
  const float* w2 = (const float*)d_in[6];
  const float* b2 = (const float*)d_in[7];
  const float* wih = (const float*)d_in[8];
  const float* whh = (const float*)d_in[9];
  const float* bih = (const float*)d_in[10];
  const float* bhh = (const float*)d_in[11];
  const float* emb = (const float*)d_in[12];
  const float* dwih = (const float*)d_in[13];
  const float* dwhh = (const float*)d_in[14];
  const float* dbih = (const float*)d_in[15];
  const float* dbhh = (const float*)d_in[16];
  const float* fcw = (const float*)d_in[17];
  const float* fcb = (const float*)d_in[18];
  float* out = (float*)d_out;
  char* ws = (char*)d_ws;

  // ws layout (bytes); xp/ip overlap dead c1out region (both written after conv2).
  unsigned short* c1out = (unsigned short*)(ws + 0);              // 78,970,880 B
  float* xp = (float*)(ws + 0);                                   // 10,321,920 B (after conv2)
  float* ipg = (float*)(ws + 13762560);                           //  6,193,152 B
  unsigned short* wt2 = (unsigned short*)(ws + 78970880);         //    589,824 B
  unsigned short* wihB = (unsigned short*)(ws + 79560704);        //    884,736 B
  unsigned int* wpe = (unsigned int*)(ws + 80445440);             //     98,304 B
  unsigned int* wpd = (unsigned int*)(ws + 80543744);             //     98,304 B
  float* wdT = (float*)(ws + 80642048);                           //     49,152 B
  unsigned short* X2 = (unsigned short*)(ws + 80691200);          // 15,482,880 B

  prep_kernel<<<3120, 256, 0, stream>>>(w2, wih, whh, dwhh, dwih, wt2, wihB, wpe, wpd, wdT);
  conv1_kernel<<<dim3(31, 64), 256, 0, stream>>>(x, mean, stdv, w1, b1, c1out);
  conv2_kernel<<<dim3(15, 64), 256, 0, stream>>>(c1out, wt2, b2, X2);
  xp_kernel<<<dim3(105, 3), 256, 0, stream>>>(X2, wihB, bih, xp);
  ip_kernel<<<64 * 63, 384, 0, stream>>>(y, emb, wdT, dbih, ipg);
  rnn_kernel<<<64, 384, 0, stream>>>(xp, wpe, bhh, ipg, wpd, dbhh, fcw, fcb, out);
}